// Round 6
// baseline (286.240 us; speedup 1.0000x reference)
//
#include <hip/hip_runtime.h>
#include <cmath>

#define HH 1024
#define WW 1024
#define KS 51
#define RAD 25
#define PLANE (HH * WW)

struct GaussW { float w[KS]; };

// ---------------------------------------------------------------------------
// FUSED 51x51 separable glow + screen blend, one kernel, one launch.
// Block = 64x64 output tile, 256 threads.
//
// Phase H: h-conv the 114 halo rows (rb-25..rb+88) x 64 cols directly from
//   global x (L3-resident) using the PROVEN R2 register-window: each lane
//   handles (row r = lane>>2, col-chunk q = lane&3): 18 float4 loads ->
//   816 FMAs -> 16 h-blurred values. Two passes cover 128>=114 rows.
//   Results go to LDS TRANSPOSED: H[col][R], row-pad 115.
//     write bank check: addr/4 mod 32 = (16(q&1)+r+115j) mod 32 -> 2 lanes/bank (free)
//     read  bank check: 115*lane mod 32 = 19*lane -> bijective mod 32 -> 2 lanes/bank (free)
// Phase V: thread = 1 col x 16 rows (R4's proven vconv): 66 scalar LDS reads
//   -> 816 FMAs -> blend with x (re-read, L1/L3-hot) -> coalesced stores.
//
// Eliminated vs two-kernel pipeline: tmp write (96 MB) + tmp fetch, vblend's
// staging phase, one launch + inter-kernel drain, chunk loop. Cost: hconv
// halo redundancy 114/64 = 1.78x (FMA +39% total). LDS 29.4 KB -> 5 blocks/CU.
// ---------------------------------------------------------------------------
__global__ __launch_bounds__(256, 4) void fused_kernel(const float* __restrict__ x,
                                                       float* __restrict__ out,
                                                       GaussW gw,
                                                       const float* __restrict__ amountp)
{
    __shared__ float H[64][115];       // 29440 B, transposed h-blur tile

    const int t    = threadIdx.x;
    const int lane = t & 63;
    const int w    = t >> 6;           // wave id, wave-uniform
    const int bid  = blockIdx.x;
    const int plane  = bid >> 8;       // 256 tiles per plane
    const int rem    = bid & 255;
    const int tile_y = rem >> 4;       // tile_x inner -> horizontal halo L2 reuse
    const int tile_x = rem & 15;
    const int cb = tile_x * 64;
    const int rb = tile_y * 64;

    const float* xp = x + (size_t)plane * PLANE;

    // ---- Phase H ----
    const int r  = lane >> 2;          // 0..15: row within 16-row group
    const int q  = lane & 3;           // 0..3 : 16-col chunk
    const int c0 = q * 16;             // local cols c0..c0+15

    #pragma unroll
    for (int p = 0; p < 2; p++) {
        const int R = p * 64 + w * 16 + r;          // 0..127; need 0..113
        if (R < 114) {
            const int grow   = rb - 25 + R;
            const bool rowok = ((unsigned)grow < (unsigned)HH);
            const float* src = xp + (size_t)(rowok ? grow : 0) * WW;

            float acc[16];
            #pragma unroll
            for (int d = 0; d < 16; d++) acc[d] = 0.f;

            // window: global cols cb+c0-28 .. cb+c0+43 (18 aligned float4)
            #pragma unroll
            for (int i = 0; i < 18; i++) {
                const int b = cb + c0 - 28 + i * 4;          // multiple of 4
                const bool ok = rowok && ((unsigned)b < (unsigned)(WW - 3));
                float4 v = *(const float4*)(src + (ok ? b : 0));
                if (!ok) v = make_float4(0.f, 0.f, 0.f, 0.f);
                const float vq[4] = {v.x, v.y, v.z, v.w};
                #pragma unroll
                for (int qq = 0; qq < 4; qq++) {
                    const int wi = i * 4 + qq;               // window index
                    #pragma unroll
                    for (int d = 0; d < 16; d++) {
                        const int k = wi - 3 - d;            // compile-time tap
                        if (k >= 0 && k < KS)
                            acc[d] = fmaf(gw.w[k], vq[qq], acc[d]);
                    }
                }
            }
            #pragma unroll
            for (int d = 0; d < 16; d++) H[c0 + d][R] = acc[d];
        }
    }
    __syncthreads();

    // ---- Phase V + blend ----
    const int lr0 = w * 16;            // output rows rb+lr0 .. rb+lr0+15

    float acc[16];
    #pragma unroll
    for (int j = 0; j < 16; j++) acc[j] = 0.f;

    #pragma unroll
    for (int i = 0; i < 66; i++) {     // input R = lr0+i, always 0..113
        const float v = H[lane][lr0 + i];
        #pragma unroll
        for (int j = 0; j < 16; j++) {
            const int k = i - j;                         // compile-time tap
            if (k >= 0 && k < KS)
                acc[j] = fmaf(gw.w[k], v, acc[j]);
        }
    }

    const float pp = amountp[0];
    const float sc = 1.2f * (0.4f / (1.f + expf(-pp)));  // 1.2 * amount

    const int c0g = cb + lane;
    const float* xr = xp + c0g;
    float*      op  = out + (size_t)plane * PLANE + c0g;
    #pragma unroll
    for (int j = 0; j < 16; j++) {
        const size_t ro = (size_t)(rb + lr0 + j) * WW;
        const float xv = xr[ro];
        float res = 1.f - (1.f - xv) * (1.f - sc * acc[j]);
        res = fminf(fmaxf(res, 0.f), 1.f);
        op[ro] = res;
    }
}

// ---------------------------------------------------------------------------
extern "C" void kernel_launch(void* const* d_in, const int* in_sizes, int n_in,
                              void* d_out, int out_size, void* d_ws, size_t ws_size,
                              hipStream_t stream)
{
    const float* x       = (const float*)d_in[0];
    const float* amountp = (const float*)d_in[1];
    float* out = (float*)d_out;
    (void)d_ws; (void)ws_size;                     // fused: no workspace needed

    // Gaussian weights (sigma=15, size 51), normalized — identical every call.
    GaussW gw;
    {
        double e[KS], sum = 0.0;
        for (int i = 0; i < KS; i++) {
            const double d = (double)(i - RAD);
            e[i] = exp(-d * d / (2.0 * 15.0 * 15.0));
            sum += e[i];
        }
        for (int i = 0; i < KS; i++) gw.w[i] = (float)(e[i] / sum);
    }

    const int total_planes = in_sizes[0] / PLANE;  // 24
    fused_kernel<<<total_planes * 256, 256, 0, stream>>>(x, out, gw, amountp);
}